// Round 3
// baseline (8723.904 us; speedup 1.0000x reference)
//
#include <hip/hip_runtime.h>
#include <hip/hip_bf16.h>

#define DEV __device__ __forceinline__

DEV float4 ld4(const float* p) { return *reinterpret_cast<const float4*>(p); }
DEV float sigmoidf_(float x) { return 1.f / (1.f + expf(-x)); }

DEV void fma8(float (&a)[8], float xv, float4 wa, float4 wb) {
  a[0] = fmaf(xv, wa.x, a[0]); a[1] = fmaf(xv, wa.y, a[1]);
  a[2] = fmaf(xv, wa.z, a[2]); a[3] = fmaf(xv, wa.w, a[3]);
  a[4] = fmaf(xv, wb.x, a[4]); a[5] = fmaf(xv, wb.y, a[5]);
  a[6] = fmaf(xv, wb.z, a[6]); a[7] = fmaf(xv, wb.w, a[7]);
}

// ---------------- CSR build (deterministic, stable) ----------------

__global__ void count_kernel(const int* __restrict__ dst, int* __restrict__ cnt, int E) {
  int e = blockIdx.x * blockDim.x + threadIdx.x;
  if (e < E) atomicAdd(&cnt[dst[e]], 1);  // counts order-independent -> deterministic
}

// hierarchical exclusive scan of cnt[0..n) -> off/cur, off[n]=total. n <= 65536.
__global__ __launch_bounds__(256) void blockreduce_kernel(const int* __restrict__ cnt,
                                                          int* __restrict__ bsum, int n) {
  int i = blockIdx.x * 256 + threadIdx.x;
  int v = (i < n) ? cnt[i] : 0;
#pragma unroll
  for (int d = 1; d < 64; d <<= 1) v += __shfl_xor(v, d, 64);
  __shared__ int sh[4];
  if ((threadIdx.x & 63) == 0) sh[threadIdx.x >> 6] = v;
  __syncthreads();
  if (threadIdx.x == 0) bsum[blockIdx.x] = sh[0] + sh[1] + sh[2] + sh[3];
}

__global__ __launch_bounds__(256) void scanb_kernel(const int* __restrict__ bsum,
                                                    int* __restrict__ boff, int nb) {
  __shared__ int sh[256];
  int t = threadIdx.x;
  int orig = (t < nb) ? bsum[t] : 0;
  int v = orig;
  sh[t] = v;
  __syncthreads();
  for (int d = 1; d < 256; d <<= 1) {
    int a = (t >= d) ? sh[t - d] : 0;
    __syncthreads();
    v += a;
    sh[t] = v;
    __syncthreads();
  }
  if (t < nb) boff[t] = v - orig;  // exclusive
}

__global__ __launch_bounds__(256) void blockscan_kernel(
    const int* __restrict__ cnt, const int* __restrict__ boff,
    int* __restrict__ off, int* __restrict__ cur, int n, int total) {
  __shared__ int sh[256];
  int b = blockIdx.x, t = threadIdx.x;
  int i = b * 256 + t;
  int orig = (i < n) ? cnt[i] : 0;
  int v = orig;
  sh[t] = v;
  __syncthreads();
  for (int d = 1; d < 256; d <<= 1) {
    int a = (t >= d) ? sh[t - d] : 0;
    __syncthreads();
    v += a;
    sh[t] = v;
    __syncthreads();
  }
  int excl = v - orig + boff[b];
  if (i < n) { off[i] = excl; cur[i] = excl; }
  if (i == n - 1) off[n] = total;
}

// phase 1: non-deterministic placement of ORIGINAL EDGE INDEX into segments
__global__ void scatter_kernel(const int* __restrict__ dstI, int* __restrict__ cur,
                               int* __restrict__ eidx, int E) {
  int e = blockIdx.x * blockDim.x + threadIdx.x;
  if (e < E) {
    int p = atomicAdd(&cur[dstI[e]], 1);
    eidx[p] = e;
  }
}

// phase 2: per-node wave rank-sort by edge index -> deterministic stable order
__global__ __launch_bounds__(256) void sortseg_kernel(
    const int* __restrict__ off, int* __restrict__ eidx,
    const int* __restrict__ srcI, const float* __restrict__ ew,
    int* __restrict__ csrc, float* __restrict__ cw, int n) {
  int node = blockIdx.x * 4 + (threadIdx.x >> 6);
  int lane = threadIdx.x & 63;
  if (node >= n) return;
  int s = off[node], e = off[node + 1];
  int deg = e - s;
  if (deg <= 0) return;
  if (deg <= 64) {
    int v = (lane < deg) ? eidx[s + lane] : 2147483647;
    int rank = 0;
    for (int m = 0; m < 64; ++m) {
      int u = __shfl(v, m, 64);
      rank += (u < v) ? 1 : 0;  // edge indices unique
    }
    if (lane < deg) {
      csrc[s + rank] = srcI[v];
      cw[s + rank]   = ew[v];
    }
  } else if (lane == 0) {
    for (int i = s + 1; i < e; ++i) {
      int key = eidx[i]; int j = i - 1;
      while (j >= s && eidx[j] > key) { eidx[j + 1] = eidx[j]; --j; }
      eidx[j + 1] = key;
    }
    for (int i = s; i < e; ++i) {
      int v = eidx[i];
      csrc[i] = srcI[v];
      cw[i]   = ew[v];
    }
  }
}

// ---------------- degree-sorted node permutation ----------------
// Per-node sums are independent of processing order, so any permutation is
// numerically identical; sorting by degree equalizes chain lengths per wave.

__global__ void deghist_kernel(const int* __restrict__ off, int* __restrict__ hist, int n) {
  int i = blockIdx.x * blockDim.x + threadIdx.x;
  if (i < n) {
    int d = min(off[i + 1] - off[i], 255);
    atomicAdd(&hist[d], 1);
  }
}

__global__ __launch_bounds__(256) void degscan_kernel(const int* __restrict__ hist,
                                                      int* __restrict__ hcur) {
  __shared__ int sh[256];
  int t = threadIdx.x;
  int orig = hist[t];
  int v = orig;
  sh[t] = v;
  __syncthreads();
  for (int d = 1; d < 256; d <<= 1) {
    int a = (t >= d) ? sh[t - d] : 0;
    __syncthreads();
    v += a;
    sh[t] = v;
    __syncthreads();
  }
  hcur[t] = v - orig;  // exclusive
}

__global__ void degplace_kernel(const int* __restrict__ off, int* __restrict__ hcur,
                                int* __restrict__ perm, int n) {
  int i = blockIdx.x * blockDim.x + threadIdx.x;
  if (i < n) {
    int d = min(off[i + 1] - off[i], 255);
    int p = atomicAdd(&hcur[d], 1);
    perm[p] = i;  // order within a degree bin is irrelevant (independent sums)
  }
}

// ---------------- aggregation (pull, CSR, 8 chains/wave) ----------------
// Exact per-node ascending-edge order (np.add.at order); __fmul_rn/__fadd_rn
// match np rounding (no fma contraction). Predicated tail adds exact 0.

__global__ __launch_bounds__(256) void aggx0_kernel(
    const int* __restrict__ off, const int* __restrict__ csrc, const float* __restrict__ cw,
    const float* __restrict__ x, float* __restrict__ ax, int n) {
  int node = blockIdx.x * 8 + (threadIdx.x >> 5);
  int lane = threadIdx.x & 31;
  if (node >= n || lane >= 24) return;
  float a = 0.f;
  int s = off[node], e = off[node + 1];
  for (int i = s; i < e; ++i)
    a = __fadd_rn(a, __fmul_rn(cw[i], x[(size_t)csrc[i] * 24 + lane]));
  ax[(size_t)node * 24 + lane] = a;
}

__global__ __launch_bounds__(256) void agg1_kernel(
    const int* __restrict__ off, const int* __restrict__ csrc, const float* __restrict__ cw,
    const int* __restrict__ perm,
    const float* __restrict__ f0, float* __restrict__ o0, int n) {
  const int wid  = blockIdx.x * 4 + (threadIdx.x >> 6);
  const int lane = threadIdx.x & 63;
  const int base = wid * 8;
  if (base >= n) return;
  int nd[8], s[8], e[8];
  int dmax = 0;
#pragma unroll
  for (int c = 0; c < 8; ++c) {
    int idx = base + c;
    int node = (idx < n) ? perm[idx] : -1;
    nd[c] = node;
    if (node >= 0) { s[c] = off[node]; e[c] = off[node + 1]; }
    else           { s[c] = 0; e[c] = 0; }
    dmax = max(dmax, e[c] - s[c]);
  }
  float acc[8];
#pragma unroll
  for (int c = 0; c < 8; ++c) acc[c] = 0.f;
  for (int k = 0; k < dmax; ++k) {
#pragma unroll
    for (int c = 0; c < 8; ++c) {
      int i = s[c] + k;
      bool ok = i < e[c];
      int ii = ok ? i : 0;
      float wv = ok ? cw[ii] : 0.f;
      int sn = csrc[ii];
      acc[c] = __fadd_rn(acc[c], __fmul_rn(wv, f0[(size_t)sn * 64 + lane]));
    }
  }
#pragma unroll
  for (int c = 0; c < 8; ++c)
    if (nd[c] >= 0) o0[(size_t)nd[c] * 64 + lane] = acc[c];
}

// fused double gather (two feature tables, shared indices): 4 nodes x 2 = 8 chains
__global__ __launch_bounds__(256) void agg2_kernel(
    const int* __restrict__ off, const int* __restrict__ csrc, const float* __restrict__ cw,
    const int* __restrict__ perm,
    const float* __restrict__ f0, float* __restrict__ o0,
    const float* __restrict__ f1, float* __restrict__ o1, int n) {
  const int wid  = blockIdx.x * 4 + (threadIdx.x >> 6);
  const int lane = threadIdx.x & 63;
  const int base = wid * 4;
  if (base >= n) return;
  int nd[4], s[4], e[4];
  int dmax = 0;
#pragma unroll
  for (int c = 0; c < 4; ++c) {
    int idx = base + c;
    int node = (idx < n) ? perm[idx] : -1;
    nd[c] = node;
    if (node >= 0) { s[c] = off[node]; e[c] = off[node + 1]; }
    else           { s[c] = 0; e[c] = 0; }
    dmax = max(dmax, e[c] - s[c]);
  }
  float a0[4], a1[4];
#pragma unroll
  for (int c = 0; c < 4; ++c) { a0[c] = 0.f; a1[c] = 0.f; }
  for (int k = 0; k < dmax; ++k) {
#pragma unroll
    for (int c = 0; c < 4; ++c) {
      int i = s[c] + k;
      bool ok = i < e[c];
      int ii = ok ? i : 0;
      float wv = ok ? cw[ii] : 0.f;
      int sn = csrc[ii];
      size_t ro = (size_t)sn * 64 + lane;
      a0[c] = __fadd_rn(a0[c], __fmul_rn(wv, f0[ro]));
      a1[c] = __fadd_rn(a1[c], __fmul_rn(wv, f1[ro]));
    }
  }
#pragma unroll
  for (int c = 0; c < 4; ++c)
    if (nd[c] >= 0) {
      o0[(size_t)nd[c] * 64 + lane] = a0[c];
      o1[(size_t)nd[c] * 64 + lane] = a1[c];
    }
}

// ---------------- gates: zr = sigmoid([aggx, aggh] @ Wg + bg); z, rh = z, r*h ----------------

template <int KX>
__global__ __launch_bounds__(256) void gates_kernel(
    const float* __restrict__ aggx, int sx,
    const float* __restrict__ aggh,
    const float* __restrict__ Wg, const float* __restrict__ bg,
    const float* __restrict__ hb, float* __restrict__ zb, float* __restrict__ rhb, int n) {
  const int t = threadIdx.x;
  const int j0 = (t & 15) * 8;
  const int r0 = blockIdx.x * 32 + (t >> 4) * 2;
  if (r0 >= n) return;
  const int r1 = r0 + 1;
  const bool v1 = r1 < n;
  float a0[8], a1[8];
#pragma unroll
  for (int i = 0; i < 8; ++i) { a0[i] = 0.f; a1[i] = 0.f; }

  {
    const float* Wh = Wg + KX * 128;
    const float* f0p = aggh + (size_t)r0 * 64;
    const float* f1p = aggh + (size_t)(v1 ? r1 : r0) * 64;
    for (int k = 0; k < 64; k += 4) {
      float4 f0 = ld4(f0p + k);
      float4 f1 = ld4(f1p + k);
#pragma unroll
      for (int kk = 0; kk < 4; ++kk) {
        const float* wr = Wh + (k + kk) * 128 + j0;
        float4 wa = ld4(wr), wb = ld4(wr + 4);
        fma8(a0, ((const float*)&f0)[kk], wa, wb);
        fma8(a1, ((const float*)&f1)[kk], wa, wb);
      }
    }
  }
  if constexpr (KX == 2) {
    float x00 = aggx[(size_t)r0 * sx], x01 = aggx[(size_t)r0 * sx + 1];
    float x10 = v1 ? aggx[(size_t)r1 * sx] : 0.f;
    float x11 = v1 ? aggx[(size_t)r1 * sx + 1] : 0.f;
#pragma unroll
    for (int k = 0; k < 2; ++k) {
      const float* wr = Wg + k * 128 + j0;
      float4 wa = ld4(wr), wb = ld4(wr + 4);
      fma8(a0, k ? x01 : x00, wa, wb);
      fma8(a1, k ? x11 : x10, wa, wb);
    }
  } else {
    const float* g0p = aggx + (size_t)r0 * sx;
    const float* g1p = aggx + (size_t)(v1 ? r1 : r0) * sx;
    for (int k = 0; k < KX; k += 4) {
      float4 f0 = ld4(g0p + k);
      float4 f1 = ld4(g1p + k);
#pragma unroll
      for (int kk = 0; kk < 4; ++kk) {
        const float* wr = Wg + (k + kk) * 128 + j0;
        float4 wa = ld4(wr), wb = ld4(wr + 4);
        fma8(a0, ((const float*)&f0)[kk], wa, wb);
        fma8(a1, ((const float*)&f1)[kk], wa, wb);
      }
    }
  }
#pragma unroll
  for (int i = 0; i < 8; ++i) {
    int j = j0 + i;
    float b = bg[j];
    float s0 = sigmoidf_(a0[i] + b);
    float s1 = sigmoidf_(a1[i] + b);
    if (j < 64) {
      zb[(size_t)r0 * 64 + j] = s0;
      if (v1) zb[(size_t)r1 * 64 + j] = s1;
    } else {
      int jj = j - 64;
      rhb[(size_t)r0 * 64 + jj] = __fmul_rn(s0, hb[(size_t)r0 * 64 + jj]);
      if (v1) rhb[(size_t)r1 * 64 + jj] = __fmul_rn(s1, hb[(size_t)r1 * 64 + jj]);
    }
  }
}

// ---------------- candidate + GRU update ----------------

template <int KX>
__global__ __launch_bounds__(256) void cand_kernel(
    const float* __restrict__ aggx, int sx,
    const float* __restrict__ aggrh,
    const float* __restrict__ Wc, const float* __restrict__ bc,
    const float* __restrict__ zb, float* __restrict__ hb,
    float* __restrict__ outp, int ostride, int n) {
  const int t = threadIdx.x;
  const int j0 = (t & 7) * 8;
  const int r0 = blockIdx.x * 64 + (t >> 3) * 2;
  if (r0 >= n) return;
  const int r1 = r0 + 1;
  const bool v1 = r1 < n;
  float a0[8], a1[8];
#pragma unroll
  for (int i = 0; i < 8; ++i) { a0[i] = 0.f; a1[i] = 0.f; }

  {
    const float* Wh = Wc + KX * 64;
    const float* f0p = aggrh + (size_t)r0 * 64;
    const float* f1p = aggrh + (size_t)(v1 ? r1 : r0) * 64;
    for (int k = 0; k < 64; k += 4) {
      float4 f0 = ld4(f0p + k);
      float4 f1 = ld4(f1p + k);
#pragma unroll
      for (int kk = 0; kk < 4; ++kk) {
        const float* wr = Wh + (k + kk) * 64 + j0;
        float4 wa = ld4(wr), wb = ld4(wr + 4);
        fma8(a0, ((const float*)&f0)[kk], wa, wb);
        fma8(a1, ((const float*)&f1)[kk], wa, wb);
      }
    }
  }
  if constexpr (KX == 2) {
    float x00 = aggx[(size_t)r0 * sx], x01 = aggx[(size_t)r0 * sx + 1];
    float x10 = v1 ? aggx[(size_t)r1 * sx] : 0.f;
    float x11 = v1 ? aggx[(size_t)r1 * sx + 1] : 0.f;
#pragma unroll
    for (int k = 0; k < 2; ++k) {
      const float* wr = Wc + k * 64 + j0;
      float4 wa = ld4(wr), wb = ld4(wr + 4);
      fma8(a0, k ? x01 : x00, wa, wb);
      fma8(a1, k ? x11 : x10, wa, wb);
    }
  } else {
    const float* g0p = aggx + (size_t)r0 * sx;
    const float* g1p = aggx + (size_t)(v1 ? r1 : r0) * sx;
    for (int k = 0; k < KX; k += 4) {
      float4 f0 = ld4(g0p + k);
      float4 f1 = ld4(g1p + k);
#pragma unroll
      for (int kk = 0; kk < 4; ++kk) {
        const float* wr = Wc + (k + kk) * 64 + j0;
        float4 wa = ld4(wr), wb = ld4(wr + 4);
        fma8(a0, ((const float*)&f0)[kk], wa, wb);
        fma8(a1, ((const float*)&f1)[kk], wa, wb);
      }
    }
  }
#pragma unroll
  for (int i = 0; i < 8; ++i) {
    int j = j0 + i;
    float b = bc[j];
    float c0 = tanhf(a0[i] + b);
    float c1 = tanhf(a1[i] + b);
    {
      float z = zb[(size_t)r0 * 64 + j];
      float h = hb[(size_t)r0 * 64 + j];
      float hn = __fadd_rn(__fmul_rn(z, h), __fmul_rn(1.f - z, c0));
      hb[(size_t)r0 * 64 + j] = hn;
      outp[(size_t)r0 * ostride + j] = hn;
    }
    if (v1) {
      float z = zb[(size_t)r1 * 64 + j];
      float h = hb[(size_t)r1 * 64 + j];
      float hn = __fadd_rn(__fmul_rn(z, h), __fmul_rn(1.f - z, c1));
      hb[(size_t)r1 * 64 + j] = hn;
      outp[(size_t)r1 * ostride + j] = hn;
    }
  }
}

// ---------------- launch ----------------

extern "C" void kernel_launch(void* const* d_in, const int* in_sizes, int n_in,
                              void* d_out, int out_size, void* d_ws, size_t ws_size,
                              hipStream_t stream) {
  const float* x   = (const float*)d_in[0];
  const float* h0  = (const float*)d_in[1];
  const int*   ei  = (const int*)  d_in[2];
  const float* ew  = (const float*)d_in[3];
  const float* Wg0 = (const float*)d_in[4];
  const float* bg0 = (const float*)d_in[5];
  const float* Wc0 = (const float*)d_in[6];
  const float* bc0 = (const float*)d_in[7];
  const float* Wg1 = (const float*)d_in[8];
  const float* bg1 = (const float*)d_in[9];
  const float* Wc1 = (const float*)d_in[10];
  const float* bc1 = (const float*)d_in[11];

  const int N = in_sizes[0] / 24;  // T*F = 24
  const int E = in_sizes[2] / 2;
  const int NH = N * 64;
  const int NB = (N + 255) / 256;  // <= 256 partial blocks

  float* h1   = (float*)d_out;      // N*64
  float* h2   = h1 + NH;            // N*64
  float* out2 = h2 + NH;            // N*T*64, layout [n][t][j]

  char* w = (char*)d_ws;
  auto alloc = [&](size_t bytes) {
    char* p = w;
    w += (bytes + 255) & ~(size_t)255;
    return p;
  };
  int*   cnt   = (int*)  alloc((size_t)N * 4);
  int*   off   = (int*)  alloc((size_t)(N + 1) * 4);
  int*   cur   = (int*)  alloc((size_t)N * 4);
  int*   csrc  = (int*)  alloc((size_t)E * 4);
  float* cw    = (float*)alloc((size_t)E * 4);
  int*   perm  = (int*)  alloc((size_t)N * 4);
  int*   bsum  = (int*)  alloc(256 * 4);
  int*   boff  = (int*)  alloc(256 * 4);
  int*   hist  = (int*)  alloc(256 * 4);
  int*   hcur  = (int*)  alloc(256 * 4);
  float* aggx0 = (float*)alloc((size_t)N * 24 * 4);
  float* aggx1 = (float*)alloc((size_t)NH * 4);
  float* aggh  = (float*)alloc((size_t)NH * 4);
  float* aggrh = (float*)alloc((size_t)NH * 4);
  float* zb    = (float*)alloc((size_t)NH * 4);
  float* rhb   = (float*)alloc((size_t)NH * 4);
  float* o1t   = (float*)alloc((size_t)NH * 4);
  int*   eidx  = (int*)aggx1;  // alias: aggx1 first used inside the t-loop

  const int* srcI = ei;
  const int* dstI = ei + E;

  hipMemcpyAsync(d_out, h0, (size_t)2 * NH * 4, hipMemcpyDeviceToDevice, stream);

  // deterministic & stable CSR: sorted by (dst, original edge index)
  hipMemsetAsync(cnt, 0, (size_t)N * 4, stream);
  hipMemsetAsync(hist, 0, 256 * 4, stream);
  count_kernel<<<(E + 255) / 256, 256, 0, stream>>>(dstI, cnt, E);
  blockreduce_kernel<<<NB, 256, 0, stream>>>(cnt, bsum, N);
  scanb_kernel<<<1, 256, 0, stream>>>(bsum, boff, NB);
  blockscan_kernel<<<NB, 256, 0, stream>>>(cnt, boff, off, cur, N, E);
  scatter_kernel<<<(E + 255) / 256, 256, 0, stream>>>(dstI, cur, eidx, E);
  sortseg_kernel<<<(N + 3) / 4, 256, 0, stream>>>(off, eidx, srcI, ew, csrc, cw, N);

  // degree-sorted permutation (numerically order-free)
  deghist_kernel<<<NB, 256, 0, stream>>>(off, hist, N);
  degscan_kernel<<<1, 256, 0, stream>>>(hist, hcur);
  degplace_kernel<<<NB, 256, 0, stream>>>(off, hcur, perm, N);

  // layer-0 x aggregation, all timesteps at once (graph is time-invariant)
  aggx0_kernel<<<(N + 7) / 8, 256, 0, stream>>>(off, csrc, cw, x, aggx0, N);

  const int g8  = (N + 31) / 32;  // agg1: 8 nodes/wave, 4 waves/block
  const int g4  = (N + 15) / 16;  // agg2: 4 nodes/wave
  const int ggat = (N + 31) / 32;
  const int gcan = (N + 63) / 64;

  for (int t = 0; t < 12; ++t) {
    // ---- layer 0 ----
    agg1_kernel<<<g8, 256, 0, stream>>>(off, csrc, cw, perm, h1, aggh, N);
    gates_kernel<2><<<ggat, 256, 0, stream>>>(aggx0 + 2 * t, 24, aggh, Wg0, bg0, h1, zb, rhb, N);
    agg1_kernel<<<g8, 256, 0, stream>>>(off, csrc, cw, perm, rhb, aggrh, N);
    cand_kernel<2><<<gcan, 256, 0, stream>>>(aggx0 + 2 * t, 24, aggrh, Wc0, bc0, zb, h1, o1t, 64, N);
    // ---- layer 1 ----
    agg2_kernel<<<g4, 256, 0, stream>>>(off, csrc, cw, perm, o1t, aggx1, h2, aggh, N);
    gates_kernel<64><<<ggat, 256, 0, stream>>>(aggx1, 64, aggh, Wg1, bg1, h2, zb, rhb, N);
    agg1_kernel<<<g8, 256, 0, stream>>>(off, csrc, cw, perm, rhb, aggrh, N);
    cand_kernel<64><<<gcan, 256, 0, stream>>>(aggx1, 64, aggrh, Wc1, bc1, zb, h2,
                                              out2 + (size_t)t * 64, 12 * 64, N);
  }
}

// Round 4
// 5777.712 us; speedup vs baseline: 1.5099x; 1.5099x over previous
//
#include <hip/hip_runtime.h>
#include <hip/hip_bf16.h>

#define DEV __device__ __forceinline__

DEV float4 ld4(const float* p) { return *reinterpret_cast<const float4*>(p); }
DEV float sigmoidf_(float x) { return 1.f / (1.f + expf(-x)); }

DEV void fma8(float (&a)[8], float xv, float4 wa, float4 wb) {
  a[0] = fmaf(xv, wa.x, a[0]); a[1] = fmaf(xv, wa.y, a[1]);
  a[2] = fmaf(xv, wa.z, a[2]); a[3] = fmaf(xv, wa.w, a[3]);
  a[4] = fmaf(xv, wb.x, a[4]); a[5] = fmaf(xv, wb.y, a[5]);
  a[6] = fmaf(xv, wb.z, a[6]); a[7] = fmaf(xv, wb.w, a[7]);
}

// ---------------- CSR build (deterministic, stable) ----------------

__global__ void count_kernel(const int* __restrict__ dst, int* __restrict__ cnt, int E) {
  int e = blockIdx.x * blockDim.x + threadIdx.x;
  if (e < E) atomicAdd(&cnt[dst[e]], 1);  // counts order-independent -> deterministic
}

// hierarchical exclusive scan of cnt[0..n) -> off/cur, off[n]=total.
__global__ __launch_bounds__(256) void blockreduce_kernel(const int* __restrict__ cnt,
                                                          int* __restrict__ bsum, int n) {
  int i = blockIdx.x * 256 + threadIdx.x;
  int v = (i < n) ? cnt[i] : 0;
#pragma unroll
  for (int d = 1; d < 64; d <<= 1) v += __shfl_xor(v, d, 64);
  __shared__ int sh[4];
  if ((threadIdx.x & 63) == 0) sh[threadIdx.x >> 6] = v;
  __syncthreads();
  if (threadIdx.x == 0) bsum[blockIdx.x] = sh[0] + sh[1] + sh[2] + sh[3];
}

__global__ __launch_bounds__(256) void scanb_kernel(const int* __restrict__ bsum,
                                                    int* __restrict__ boff, int nb) {
  __shared__ int sh[256];
  int t = threadIdx.x;
  int orig = (t < nb) ? bsum[t] : 0;
  int v = orig;
  sh[t] = v;
  __syncthreads();
  for (int d = 1; d < 256; d <<= 1) {
    int a = (t >= d) ? sh[t - d] : 0;
    __syncthreads();
    v += a;
    sh[t] = v;
    __syncthreads();
  }
  if (t < nb) boff[t] = v - orig;  // exclusive
}

__global__ __launch_bounds__(256) void blockscan_kernel(
    const int* __restrict__ cnt, const int* __restrict__ boff,
    int* __restrict__ off, int* __restrict__ cur, int n, int total) {
  __shared__ int sh[256];
  int b = blockIdx.x, t = threadIdx.x;
  int i = b * 256 + t;
  int orig = (i < n) ? cnt[i] : 0;
  int v = orig;
  sh[t] = v;
  __syncthreads();
  for (int d = 1; d < 256; d <<= 1) {
    int a = (t >= d) ? sh[t - d] : 0;
    __syncthreads();
    v += a;
    sh[t] = v;
    __syncthreads();
  }
  int excl = v - orig + boff[b];
  if (i < n) { off[i] = excl; cur[i] = excl; }
  if (i == n - 1) off[n] = total;
}

// phase 1: non-deterministic placement of ORIGINAL EDGE INDEX into segments
__global__ void scatter_kernel(const int* __restrict__ dstI, int* __restrict__ cur,
                               int* __restrict__ eidx, int E) {
  int e = blockIdx.x * blockDim.x + threadIdx.x;
  if (e < E) {
    int p = atomicAdd(&cur[dstI[e]], 1);
    eidx[p] = e;
  }
}

// phase 2: per-node wave rank-sort by edge index -> deterministic stable order
// (ascending edge index == np.add.at accumulation order)
__global__ __launch_bounds__(256) void sortseg_kernel(
    const int* __restrict__ off, int* __restrict__ eidx,
    const int* __restrict__ srcI, const float* __restrict__ ew,
    int* __restrict__ csrc, float* __restrict__ cw, int n) {
  int node = blockIdx.x * 4 + (threadIdx.x >> 6);
  int lane = threadIdx.x & 63;
  if (node >= n) return;
  int s = off[node], e = off[node + 1];
  int deg = e - s;
  if (deg <= 0) return;
  if (deg <= 64) {
    int v = (lane < deg) ? eidx[s + lane] : 2147483647;
    int rank = 0;
    for (int m = 0; m < 64; ++m) {
      int u = __shfl(v, m, 64);
      rank += (u < v) ? 1 : 0;  // edge indices unique
    }
    if (lane < deg) {
      csrc[s + rank] = srcI[v];
      cw[s + rank]   = ew[v];
    }
  } else if (lane == 0) {
    for (int i = s + 1; i < e; ++i) {
      int key = eidx[i]; int j = i - 1;
      while (j >= s && eidx[j] > key) { eidx[j + 1] = eidx[j]; --j; }
      eidx[j + 1] = key;
    }
    for (int i = s; i < e; ++i) {
      int v = eidx[i];
      csrc[i] = srcI[v];
      cw[i]   = ew[v];
    }
  }
}

// ---------------- aggregation (pull, CSR) ----------------
// 16-lane group per node, float4 per lane => one full 256B row per edge-step.
// Per-feature accumulation is strictly ascending edge order (np.add.at order);
// __fmul_rn/__fadd_rn match np rounding (no fma contraction). Bit-identical
// to the 1-node/wave scalar version.

DEV float4 wfma4(float4 a, float w, float4 r) {
  a.x = __fadd_rn(a.x, __fmul_rn(w, r.x));
  a.y = __fadd_rn(a.y, __fmul_rn(w, r.y));
  a.z = __fadd_rn(a.z, __fmul_rn(w, r.z));
  a.w = __fadd_rn(a.w, __fmul_rn(w, r.w));
  return a;
}

__global__ __launch_bounds__(256) void aggx0_kernel(
    const int* __restrict__ off, const int* __restrict__ csrc, const float* __restrict__ cw,
    const float* __restrict__ x, float* __restrict__ ax, int n) {
  int node = blockIdx.x * 8 + (threadIdx.x >> 5);
  int lane = threadIdx.x & 31;
  if (node >= n || lane >= 24) return;
  float a = 0.f;
  int s = off[node], e = off[node + 1];
  for (int i = s; i < e; ++i)
    a = __fadd_rn(a, __fmul_rn(cw[i], x[(size_t)csrc[i] * 24 + lane]));
  ax[(size_t)node * 24 + lane] = a;
}

__global__ __launch_bounds__(256) void agg1_kernel(
    const int* __restrict__ off, const int* __restrict__ csrc, const float* __restrict__ cw,
    const float* __restrict__ f0, float* __restrict__ o0, int n) {
  const int node = blockIdx.x * 16 + (threadIdx.x >> 4);  // 16-lane group per node
  const int g4   = (threadIdx.x & 15) * 4;                // feature quad
  if (node >= n) return;
  int s = off[node], e = off[node + 1];
  float4 acc = make_float4(0.f, 0.f, 0.f, 0.f);
  for (int i = s; i < e; ++i) {
    float w = cw[i];
    int sn = csrc[i];
    acc = wfma4(acc, w, ld4(f0 + (size_t)sn * 64 + g4));
  }
  *reinterpret_cast<float4*>(o0 + (size_t)node * 64 + g4) = acc;
}

// fused double gather (two feature tables, shared index stream)
__global__ __launch_bounds__(256) void agg2_kernel(
    const int* __restrict__ off, const int* __restrict__ csrc, const float* __restrict__ cw,
    const float* __restrict__ f0, float* __restrict__ o0,
    const float* __restrict__ f1, float* __restrict__ o1, int n) {
  const int node = blockIdx.x * 16 + (threadIdx.x >> 4);
  const int g4   = (threadIdx.x & 15) * 4;
  if (node >= n) return;
  int s = off[node], e = off[node + 1];
  float4 a0 = make_float4(0.f, 0.f, 0.f, 0.f);
  float4 a1 = a0;
  for (int i = s; i < e; ++i) {
    float w = cw[i];
    int sn = csrc[i];
    size_t ro = (size_t)sn * 64 + g4;
    a0 = wfma4(a0, w, ld4(f0 + ro));
    a1 = wfma4(a1, w, ld4(f1 + ro));
  }
  *reinterpret_cast<float4*>(o0 + (size_t)node * 64 + g4) = a0;
  *reinterpret_cast<float4*>(o1 + (size_t)node * 64 + g4) = a1;
}

// ---------------- gates: zr = sigmoid([aggx, aggh] @ Wg + bg); z, rh = z, r*h ----------------

template <int KX>
__global__ __launch_bounds__(256) void gates_kernel(
    const float* __restrict__ aggx, int sx,
    const float* __restrict__ aggh,
    const float* __restrict__ Wg, const float* __restrict__ bg,
    const float* __restrict__ hb, float* __restrict__ zb, float* __restrict__ rhb, int n) {
  const int t = threadIdx.x;
  const int j0 = (t & 15) * 8;
  const int r0 = blockIdx.x * 32 + (t >> 4) * 2;
  if (r0 >= n) return;
  const int r1 = r0 + 1;
  const bool v1 = r1 < n;
  float a0[8], a1[8];
#pragma unroll
  for (int i = 0; i < 8; ++i) { a0[i] = 0.f; a1[i] = 0.f; }

  {
    const float* Wh = Wg + KX * 128;
    const float* f0p = aggh + (size_t)r0 * 64;
    const float* f1p = aggh + (size_t)(v1 ? r1 : r0) * 64;
    for (int k = 0; k < 64; k += 4) {
      float4 f0 = ld4(f0p + k);
      float4 f1 = ld4(f1p + k);
#pragma unroll
      for (int kk = 0; kk < 4; ++kk) {
        const float* wr = Wh + (k + kk) * 128 + j0;
        float4 wa = ld4(wr), wb = ld4(wr + 4);
        fma8(a0, ((const float*)&f0)[kk], wa, wb);
        fma8(a1, ((const float*)&f1)[kk], wa, wb);
      }
    }
  }
  if constexpr (KX == 2) {
    float x00 = aggx[(size_t)r0 * sx], x01 = aggx[(size_t)r0 * sx + 1];
    float x10 = v1 ? aggx[(size_t)r1 * sx] : 0.f;
    float x11 = v1 ? aggx[(size_t)r1 * sx + 1] : 0.f;
#pragma unroll
    for (int k = 0; k < 2; ++k) {
      const float* wr = Wg + k * 128 + j0;
      float4 wa = ld4(wr), wb = ld4(wr + 4);
      fma8(a0, k ? x01 : x00, wa, wb);
      fma8(a1, k ? x11 : x10, wa, wb);
    }
  } else {
    const float* g0p = aggx + (size_t)r0 * sx;
    const float* g1p = aggx + (size_t)(v1 ? r1 : r0) * sx;
    for (int k = 0; k < KX; k += 4) {
      float4 f0 = ld4(g0p + k);
      float4 f1 = ld4(g1p + k);
#pragma unroll
      for (int kk = 0; kk < 4; ++kk) {
        const float* wr = Wg + (k + kk) * 128 + j0;
        float4 wa = ld4(wr), wb = ld4(wr + 4);
        fma8(a0, ((const float*)&f0)[kk], wa, wb);
        fma8(a1, ((const float*)&f1)[kk], wa, wb);
      }
    }
  }
#pragma unroll
  for (int i = 0; i < 8; ++i) {
    int j = j0 + i;
    float b = bg[j];
    float s0 = sigmoidf_(a0[i] + b);
    float s1 = sigmoidf_(a1[i] + b);
    if (j < 64) {
      zb[(size_t)r0 * 64 + j] = s0;
      if (v1) zb[(size_t)r1 * 64 + j] = s1;
    } else {
      int jj = j - 64;
      rhb[(size_t)r0 * 64 + jj] = __fmul_rn(s0, hb[(size_t)r0 * 64 + jj]);
      if (v1) rhb[(size_t)r1 * 64 + jj] = __fmul_rn(s1, hb[(size_t)r1 * 64 + jj]);
    }
  }
}

// ---------------- candidate + GRU update ----------------

template <int KX>
__global__ __launch_bounds__(256) void cand_kernel(
    const float* __restrict__ aggx, int sx,
    const float* __restrict__ aggrh,
    const float* __restrict__ Wc, const float* __restrict__ bc,
    const float* __restrict__ zb, float* __restrict__ hb,
    float* __restrict__ outp, int ostride, int n) {
  const int t = threadIdx.x;
  const int j0 = (t & 7) * 8;
  const int r0 = blockIdx.x * 64 + (t >> 3) * 2;
  if (r0 >= n) return;
  const int r1 = r0 + 1;
  const bool v1 = r1 < n;
  float a0[8], a1[8];
#pragma unroll
  for (int i = 0; i < 8; ++i) { a0[i] = 0.f; a1[i] = 0.f; }

  {
    const float* Wh = Wc + KX * 64;
    const float* f0p = aggrh + (size_t)r0 * 64;
    const float* f1p = aggrh + (size_t)(v1 ? r1 : r0) * 64;
    for (int k = 0; k < 64; k += 4) {
      float4 f0 = ld4(f0p + k);
      float4 f1 = ld4(f1p + k);
#pragma unroll
      for (int kk = 0; kk < 4; ++kk) {
        const float* wr = Wh + (k + kk) * 64 + j0;
        float4 wa = ld4(wr), wb = ld4(wr + 4);
        fma8(a0, ((const float*)&f0)[kk], wa, wb);
        fma8(a1, ((const float*)&f1)[kk], wa, wb);
      }
    }
  }
  if constexpr (KX == 2) {
    float x00 = aggx[(size_t)r0 * sx], x01 = aggx[(size_t)r0 * sx + 1];
    float x10 = v1 ? aggx[(size_t)r1 * sx] : 0.f;
    float x11 = v1 ? aggx[(size_t)r1 * sx + 1] : 0.f;
#pragma unroll
    for (int k = 0; k < 2; ++k) {
      const float* wr = Wc + k * 64 + j0;
      float4 wa = ld4(wr), wb = ld4(wr + 4);
      fma8(a0, k ? x01 : x00, wa, wb);
      fma8(a1, k ? x11 : x10, wa, wb);
    }
  } else {
    const float* g0p = aggx + (size_t)r0 * sx;
    const float* g1p = aggx + (size_t)(v1 ? r1 : r0) * sx;
    for (int k = 0; k < KX; k += 4) {
      float4 f0 = ld4(g0p + k);
      float4 f1 = ld4(g1p + k);
#pragma unroll
      for (int kk = 0; kk < 4; ++kk) {
        const float* wr = Wc + (k + kk) * 64 + j0;
        float4 wa = ld4(wr), wb = ld4(wr + 4);
        fma8(a0, ((const float*)&f0)[kk], wa, wb);
        fma8(a1, ((const float*)&f1)[kk], wa, wb);
      }
    }
  }
#pragma unroll
  for (int i = 0; i < 8; ++i) {
    int j = j0 + i;
    float b = bc[j];
    float c0 = tanhf(a0[i] + b);
    float c1 = tanhf(a1[i] + b);
    {
      float z = zb[(size_t)r0 * 64 + j];
      float h = hb[(size_t)r0 * 64 + j];
      float hn = __fadd_rn(__fmul_rn(z, h), __fmul_rn(1.f - z, c0));
      hb[(size_t)r0 * 64 + j] = hn;
      outp[(size_t)r0 * ostride + j] = hn;
    }
    if (v1) {
      float z = zb[(size_t)r1 * 64 + j];
      float h = hb[(size_t)r1 * 64 + j];
      float hn = __fadd_rn(__fmul_rn(z, h), __fmul_rn(1.f - z, c1));
      hb[(size_t)r1 * 64 + j] = hn;
      outp[(size_t)r1 * ostride + j] = hn;
    }
  }
}

// ---------------- launch ----------------

extern "C" void kernel_launch(void* const* d_in, const int* in_sizes, int n_in,
                              void* d_out, int out_size, void* d_ws, size_t ws_size,
                              hipStream_t stream) {
  const float* x   = (const float*)d_in[0];
  const float* h0  = (const float*)d_in[1];
  const int*   ei  = (const int*)  d_in[2];
  const float* ew  = (const float*)d_in[3];
  const float* Wg0 = (const float*)d_in[4];
  const float* bg0 = (const float*)d_in[5];
  const float* Wc0 = (const float*)d_in[6];
  const float* bc0 = (const float*)d_in[7];
  const float* Wg1 = (const float*)d_in[8];
  const float* bg1 = (const float*)d_in[9];
  const float* Wc1 = (const float*)d_in[10];
  const float* bc1 = (const float*)d_in[11];

  const int N = in_sizes[0] / 24;  // T*F = 24
  const int E = in_sizes[2] / 2;
  const int NH = N * 64;
  const int NB = (N + 255) / 256;  // <= 256 partial blocks

  float* h1   = (float*)d_out;      // N*64
  float* h2   = h1 + NH;            // N*64
  float* out2 = h2 + NH;            // N*T*64, layout [n][t][j]

  char* w = (char*)d_ws;
  auto alloc = [&](size_t bytes) {
    char* p = w;
    w += (bytes + 255) & ~(size_t)255;
    return p;
  };
  int*   cnt   = (int*)  alloc((size_t)N * 4);
  int*   off   = (int*)  alloc((size_t)(N + 1) * 4);
  int*   cur   = (int*)  alloc((size_t)N * 4);
  int*   csrc  = (int*)  alloc((size_t)E * 4);
  float* cw    = (float*)alloc((size_t)E * 4);
  int*   bsum  = (int*)  alloc(256 * 4);
  int*   boff  = (int*)  alloc(256 * 4);
  float* aggx0 = (float*)alloc((size_t)N * 24 * 4);
  float* aggx1 = (float*)alloc((size_t)NH * 4);
  float* aggh  = (float*)alloc((size_t)NH * 4);
  float* aggrh = (float*)alloc((size_t)NH * 4);
  float* zb    = (float*)alloc((size_t)NH * 4);
  float* rhb   = (float*)alloc((size_t)NH * 4);
  float* o1t   = (float*)alloc((size_t)NH * 4);
  int*   eidx  = (int*)aggx1;  // alias: aggx1 first used inside the t-loop

  const int* srcI = ei;
  const int* dstI = ei + E;

  hipMemcpyAsync(d_out, h0, (size_t)2 * NH * 4, hipMemcpyDeviceToDevice, stream);

  // deterministic & stable CSR: sorted by (dst, original edge index)
  hipMemsetAsync(cnt, 0, (size_t)N * 4, stream);
  count_kernel<<<(E + 255) / 256, 256, 0, stream>>>(dstI, cnt, E);
  blockreduce_kernel<<<NB, 256, 0, stream>>>(cnt, bsum, N);
  scanb_kernel<<<1, 256, 0, stream>>>(bsum, boff, NB);
  blockscan_kernel<<<NB, 256, 0, stream>>>(cnt, boff, off, cur, N, E);
  scatter_kernel<<<(E + 255) / 256, 256, 0, stream>>>(dstI, cur, eidx, E);
  sortseg_kernel<<<(N + 3) / 4, 256, 0, stream>>>(off, eidx, srcI, ew, csrc, cw, N);

  // layer-0 x aggregation, all timesteps at once (graph is time-invariant)
  aggx0_kernel<<<(N + 7) / 8, 256, 0, stream>>>(off, csrc, cw, x, aggx0, N);

  const int gagg = (N + 15) / 16;  // 16 nodes/block (16-lane group per node)
  const int ggat = (N + 31) / 32;
  const int gcan = (N + 63) / 64;

  for (int t = 0; t < 12; ++t) {
    // ---- layer 0 ----
    agg1_kernel<<<gagg, 256, 0, stream>>>(off, csrc, cw, h1, aggh, N);
    gates_kernel<2><<<ggat, 256, 0, stream>>>(aggx0 + 2 * t, 24, aggh, Wg0, bg0, h1, zb, rhb, N);
    agg1_kernel<<<gagg, 256, 0, stream>>>(off, csrc, cw, rhb, aggrh, N);
    cand_kernel<2><<<gcan, 256, 0, stream>>>(aggx0 + 2 * t, 24, aggrh, Wc0, bc0, zb, h1, o1t, 64, N);
    // ---- layer 1 ----
    agg2_kernel<<<gagg, 256, 0, stream>>>(off, csrc, cw, o1t, aggx1, h2, aggh, N);
    gates_kernel<64><<<ggat, 256, 0, stream>>>(aggx1, 64, aggh, Wg1, bg1, h2, zb, rhb, N);
    agg1_kernel<<<gagg, 256, 0, stream>>>(off, csrc, cw, rhb, aggrh, N);
    cand_kernel<64><<<gcan, 256, 0, stream>>>(aggx1, 64, aggrh, Wc1, bc1, zb, h2,
                                              out2 + (size_t)t * 64, 12 * 64, N);
  }
}